// Round 2
// baseline (403.984 us; speedup 1.0000x reference)
//
#include <hip/hip_runtime.h>
#include <hip/hip_cooperative_groups.h>
#include <math.h>

// ForwardDiffusion: x_t = a*x_{t-1} + c*z_t, a = 1-THETA*DT, c = SIGMA0*sqrt(DT).
// Noise is batch-independent => closed form x_t[b,l] = a^t * x0[b,l] + c * S_t[l],
// S_t[l] = a*S_{t-1}[l] + z_t[l] (single (999,1024) scan, no per-batch scan).
//
// R2 change: fuse partial/combine/emit into ONE cooperative kernel with two
// grid syncs. Kills 2 inter-kernel graph gaps, the 4-block k_combine latency
// tail, and emit's ragged dispatch tail (4032 tiles / 504 blocks = exactly 8
// tiles per block, 512KB contiguous writes each). Store path unchanged (nt).
//
// ws layout (floats): S[STEPS*LEN] | carry[NCHUNK*LEN] | apow[STEPS]

namespace cg = cooperative_groups;

namespace {
constexpr int LEN    = 1024;
constexpr int BATCH  = 64;
constexpr int STEPS  = 1000;
constexpr int NST    = 999;
constexpr int CHUNK  = 16;
constexpr int NCHUNK = (NST + CHUNK - 1) / CHUNK;  // 63
constexpr int GRID   = 504;                        // 4032 tiles / 8 per block
constexpr float THETA = 1.0f;
constexpr float DT    = 0.001f;
typedef float f32x4 __attribute__((ext_vector_type(4)));
}

// 504 blocks x 256 threads, co-resident at 2 blocks/CU (launch_bounds(256,2)
// caps VGPR at 256 -> co-residency guaranteed; cooperative launch required
// for grid.sync validity).
__global__ __launch_bounds__(256, 2) void k_fused(const float* __restrict__ x0,
                                                  const float* __restrict__ noise,
                                                  float* __restrict__ S,
                                                  float* __restrict__ carry,
                                                  float* __restrict__ apow,
                                                  float* __restrict__ out) {
    const int tid = threadIdx.x;
    const int blk = blockIdx.x;
    const float a = 1.0f - THETA * DT;

    // ---- Phase 1: per-chunk local scans (252 units: 63 chunks x 4 col-groups)
    if (blk < NCHUNK * 4) {
        const int g = blk >> 2;
        const int l = (blk & 3) * 256 + tid;
        if (g == 0) S[l] = 0.0f;                    // t = 0 row
        const int t0 = g * CHUNK + 1;
        const int t1 = min((g + 1) * CHUNK, NST);
        float acc = 0.0f;
        #pragma unroll
        for (int t = t0; t <= t1; ++t) {
            acc = a * acc + noise[(t - 1) * LEN + l];
            S[t * LEN + l] = acc;
        }
    }
    cg::this_grid().sync();

    // ---- Phase 2: combine chunk carries (4 blocks; others wait at sync).
    if (blk < 4) {
        const int l = blk * 256 + tid;
        if (l < STEPS) apow[l] = powf(a, (float)l);
        float vals[NCHUNK];
        #pragma unroll
        for (int g = 0; g < NCHUNK; ++g) {
            const int t1 = min((g + 1) * CHUNK, NST);
            vals[g] = S[t1 * LEN + l];               // independent, pipelined
        }
        const float a16 = 0.98411684f;               // (1-0.001)^16
        float cr = 0.0f;
        #pragma unroll
        for (int g = 0; g < NCHUNK; ++g) {
            carry[g * LEN + l] = cr;
            cr = a16 * cr + vals[g];
        }
    }
    cg::this_grid().sync();

    // ---- Phase 3: emit. Tile (b,g) = 16 rows (7 for g=62), 8 tiles/block,
    // b-major so each block's 8 tiles are a contiguous ~512KB output region.
    const float c = 0.5f * sqrtf(DT);
    #pragma unroll 1
    for (int it = 0; it < 8; ++it) {
        const int tile = blk * 8 + it;
        const int b = tile / NCHUNK;
        const int g = tile - b * NCHUNK;
        const int tbase = g * CHUNK;

        const f32x4 x   = ((const f32x4*)(x0 + b * LEN))[tid];
        const f32x4 ccr = c * ((const f32x4*)(carry + g * LEN))[tid];
        float* outb = out + (size_t)b * STEPS * LEN;

        if (g == 0) {
            // t = 0: apow[0]=1, S row 0 zero, carry row 0 zero -> out = x.
            __builtin_nontemporal_store(x, (f32x4*)outb + tid);
        }

        auto emit1 = [&](int i) {
            const int t = tbase + i;
            const float ap  = apow[t];
            const float apl = apow[i];
            const f32x4 s = ((const f32x4*)(S + (size_t)t * LEN))[tid];
            f32x4 o = ap * x + c * s + apl * ccr;
            __builtin_nontemporal_store(o, (f32x4*)(outb + (size_t)t * LEN) + tid);
        };

        if (g != NCHUNK - 1) {
            #pragma unroll
            for (int i = 1; i <= CHUNK; ++i) emit1(i);
        } else {                                     // g = 62: t = 993..999
            #pragma unroll
            for (int i = 1; i <= NST - (NCHUNK - 1) * CHUNK; ++i) emit1(i);
        }
    }
}

extern "C" void kernel_launch(void* const* d_in, const int* in_sizes, int n_in,
                              void* d_out, int out_size, void* d_ws, size_t ws_size,
                              hipStream_t stream) {
    const float* x     = (const float*)d_in[0];   // (64, 1024) fp32
    const float* noise = (const float*)d_in[1];   // (999, 1024) fp32
    float* out = (float*)d_out;                   // (64, 1000, 1024) fp32
    float* ws  = (float*)d_ws;

    float* S     = ws;                      // STEPS*LEN
    float* carry = S + STEPS * LEN;         // NCHUNK*LEN
    float* apow  = carry + NCHUNK * LEN;    // STEPS

    void* args[] = {(void*)&x, (void*)&noise, (void*)&S, (void*)&carry,
                    (void*)&apow, (void*)&out};
    hipLaunchCooperativeKernel((const void*)k_fused, dim3(GRID), dim3(256),
                               args, 0, stream);
}

// Round 3
// 269.441 us; speedup vs baseline: 1.4993x; 1.4993x over previous
//
#include <hip/hip_runtime.h>
#include <math.h>

// ForwardDiffusion: x_t = a*x_{t-1} + c*z_t, a = 1-THETA*DT, c = SIGMA0*sqrt(DT).
// Noise is batch-independent => closed form x_t[b,l] = a^t * x0[b,l] + c * S_t[l],
// S_t[l] = a*S_{t-1}[l] + z_t[l] (single (999,1024) scan, no per-batch scan).
//
// ws layout (floats): S[STEPS*LEN] | carry[NCHUNK*LEN] | apow[STEPS]
//
// R3 change (single variable vs R1): emit uses PLAIN f32x4 stores instead of
// __builtin_nontemporal_store. Theory: nt 16B stores bypass L2 write-combining
// -> sub-line HBM writes -> ~3.5 TB/s effective; plain stores ride the same
// L2 writeback path the 6.3 TB/s poison-fill uses. R2's cooperative fusion is
// reverted (504-block grid = 8 waves/CU could only do 1.5-1.9 TB/s).

namespace {
constexpr int LEN    = 1024;
constexpr int BATCH  = 64;
constexpr int STEPS  = 1000;
constexpr int NST    = 999;
constexpr int CHUNK  = 16;
constexpr int NCHUNK = (NST + CHUNK - 1) / CHUNK;  // 63
constexpr float THETA = 1.0f;
constexpr float DT    = 0.001f;
typedef float f32x4 __attribute__((ext_vector_type(4)));
}

// Kernel 1: per-chunk local scans, carry-in 0. grid (NCHUNK, 4) x 256 threads.
__global__ __launch_bounds__(256) void k_partial(const float* __restrict__ noise,
                                                 float* __restrict__ S) {
    const int l = blockIdx.y * 256 + threadIdx.x;
    const int g = blockIdx.x;
    const float a = 1.0f - THETA * DT;
    if (g == 0) S[l] = 0.0f;
    const int t0 = g * CHUNK + 1;
    const int t1 = min((g + 1) * CHUNK, NST);
    float acc = 0.0f;
    #pragma unroll
    for (int t = t0; t <= t1; ++t) {
        acc = a * acc + noise[(t - 1) * LEN + l];
        S[t * LEN + l] = acc;
    }
}

// Kernel 2: combine chunk carries. grid (4) x 256 threads. Independent S-loads
// prefetched into registers before the serial FMA chain. Also builds a^t table.
__global__ __launch_bounds__(256) void k_combine(const float* __restrict__ S,
                                                 float* __restrict__ carry,
                                                 float* __restrict__ apow) {
    const int l = blockIdx.x * 256 + threadIdx.x;
    const float a = 1.0f - THETA * DT;
    if (l < STEPS) apow[l] = powf(a, (float)l);

    float vals[NCHUNK];
    #pragma unroll
    for (int g = 0; g < NCHUNK; ++g) {
        const int t1 = min((g + 1) * CHUNK, NST);
        vals[g] = S[t1 * LEN + l];           // independent loads, pipelined
    }
    const float a16 = 0.98411684f;           // (1-0.001)^16
    float cr = 0.0f;
    #pragma unroll
    for (int g = 0; g < NCHUNK; ++g) {
        carry[g * LEN + l] = cr;
        cr = a16 * cr + vals[g];
    }
}

// Kernel 3: out[b][t][l] = a^t * x0[b,l] + c*S[t][l] + (c*a^tloc)*carry[g][l].
// grid (BATCH, NCHUNK) x 256: block (b,g) emits the 16 chunk-aligned rows
// (carry row block-constant, x loaded once, 64KB contiguous writes).
__global__ __launch_bounds__(256) void k_emit(const float* __restrict__ x0,
                                              const float* __restrict__ S,
                                              const float* __restrict__ carry,
                                              const float* __restrict__ apow,
                                              float* __restrict__ out) {
    const int b = blockIdx.x;
    const int g = blockIdx.y;
    const float c = 0.5f * sqrtf(DT);
    const int l4 = threadIdx.x;
    const f32x4 x   = ((const f32x4*)(x0 + b * LEN))[l4];
    const f32x4 ccr = c * ((const f32x4*)(carry + g * LEN))[l4];
    float* outb = out + (size_t)b * STEPS * LEN;

    if (g == 0) {
        // t = 0: apow[0]=1, S row 0 zero, carry row 0 zero -> out = x.
        ((f32x4*)outb)[l4] = x;
    }
    const int tbase = g * CHUNK;

    auto emit1 = [&](int i) {
        const int t = tbase + i;
        const float ap  = apow[t];
        const float apl = apow[i];
        const f32x4 s = ((const f32x4*)(S + (size_t)t * LEN))[l4];
        f32x4 o = ap * x + c * s + apl * ccr;
        ((f32x4*)(outb + (size_t)t * LEN))[l4] = o;   // PLAIN store (R3 change)
    };

    if (g != NCHUNK - 1) {
        #pragma unroll
        for (int i = 1; i <= CHUNK; ++i) emit1(i);
    } else {                                 // g = 62: t = 993..999 (7 rows)
        #pragma unroll
        for (int i = 1; i <= NST - (NCHUNK - 1) * CHUNK; ++i) emit1(i);
    }
}

extern "C" void kernel_launch(void* const* d_in, const int* in_sizes, int n_in,
                              void* d_out, int out_size, void* d_ws, size_t ws_size,
                              hipStream_t stream) {
    const float* x     = (const float*)d_in[0];   // (64, 1024) fp32
    const float* noise = (const float*)d_in[1];   // (999, 1024) fp32
    float* out = (float*)d_out;                   // (64, 1000, 1024) fp32
    float* ws  = (float*)d_ws;

    float* S     = ws;                      // STEPS*LEN
    float* carry = S + STEPS * LEN;         // NCHUNK*LEN
    float* apow  = carry + NCHUNK * LEN;    // STEPS

    hipLaunchKernelGGL(k_partial, dim3(NCHUNK, 4), dim3(256), 0, stream, noise, S);
    hipLaunchKernelGGL(k_combine, dim3(4), dim3(256), 0, stream, S, carry, apow);
    hipLaunchKernelGGL(k_emit, dim3(BATCH, NCHUNK), dim3(256), 0, stream,
                       x, S, carry, apow, out);
}